// Round 8
// baseline (200.463 us; speedup 1.0000x reference)
//
#include <hip/hip_runtime.h>

#define F_IN   128
#define HIDDEN 256
#define NCLS   4

#define BSH    7          // log2(nodes per bucket)
#define BNODES 128        // nodes per bucket
#define BCAP   3072       // max edges per bucket region (mean 2048, +22 sigma)
#define CHUNK  4096       // edges per k_bin workgroup
#define MROWS  32         // nodes per k_fused block (2 MFMA row-tiles)

typedef __attribute__((ext_vector_type(8))) short short8;
typedef __attribute__((ext_vector_type(4))) float f32x4;

__device__ __forceinline__ unsigned short f2bf(float f) {
    unsigned int u = __float_as_uint(f);
    return (unsigned short)((u + 0x7fffu + ((u >> 16) & 1u)) >> 16);  // RNE
}

__device__ __forceinline__ float bflo(unsigned int u) { return __uint_as_float(u << 16); }
__device__ __forceinline__ float bfhi(unsigned int u) { return __uint_as_float(u & 0xffff0000u); }

// ---------------- pass A: bin edges into per-bucket regions ----------------
// word = (dst_local << 16) | src   (src < 65536, dst_local < 128)

__global__ __launch_bounds__(256) void k_bin(const int* __restrict__ srcIdx,
                                             const int* __restrict__ dstIdx,
                                             int* __restrict__ cursor,
                                             unsigned int* __restrict__ inter,
                                             int E, int nbuk) {
    __shared__ int cntS[512], bA[512], bB[512], curS[512], eS[512], gS[512];
    __shared__ unsigned int stag[CHUNK];
    __shared__ unsigned short bb[CHUNK];
    int t = threadIdx.x;
    int e0 = blockIdx.x * CHUNK;
    int n = E - e0; if (n > CHUNK) n = CHUNK;

    cntS[t] = 0; cntS[t + 256] = 0;
    __syncthreads();
    for (int i = t; i < n; i += 256)
        atomicAdd(&cntS[dstIdx[e0 + i] >> BSH], 1);
    __syncthreads();

    int* pa = bA; int* pb = bB;
    bA[t] = cntS[t]; bA[t + 256] = cntS[t + 256];
    __syncthreads();
    for (int off = 1; off < 512; off <<= 1) {
        pb[t] = pa[t] + (t >= off ? pa[t - off] : 0);
        int p1 = t + 256;
        pb[p1] = pa[p1] + (p1 >= off ? pa[p1 - off] : 0);
        __syncthreads();
        int* tmp = pa; pa = pb; pb = tmp;
    }
    eS[t] = pa[t] - cntS[t];
    curS[t] = eS[t];
    int p1 = t + 256;
    eS[p1] = pa[p1] - cntS[p1];
    curS[p1] = eS[p1];
    __syncthreads();

    for (int i = t; i < nbuk; i += 256) {
        int c = cntS[i];
        gS[i] = (c > 0) ? atomicAdd(&cursor[i], c) : 0;
    }
    __syncthreads();

    for (int i = t; i < n; i += 256) {
        int d = dstIdx[e0 + i];
        int s = srcIdx[e0 + i];
        int b = d >> BSH;
        unsigned int w = ((unsigned int)(d & (BNODES - 1)) << 16) | (unsigned int)s;
        int off = atomicAdd(&curS[b], 1);
        stag[off] = w;
        bb[off] = (unsigned short)b;
    }
    __syncthreads();

    for (int i = t; i < n; i += 256) {
        int b = bb[i];
        inter[(size_t)b * BCAP + gS[b] + (i - eS[b])] = stag[i];
    }
}

// ---------------- pass B: per-bucket count + scan + fine scatter ----------------
// Inlines the bucket-base prefix (sum of cursor[0..b)). Writes rowptr, dis,
// csr16 (ushort src grouped by dst), and fused xs = bf16(dis*x).

__global__ __launch_bounds__(256) void k_bucket_build(const unsigned int* __restrict__ inter,
                                                      const int* __restrict__ cursor,
                                                      const float2* __restrict__ x2,
                                                      int* __restrict__ rowptr,
                                                      float* __restrict__ dis,
                                                      unsigned int* __restrict__ xs,
                                                      unsigned short* __restrict__ csr16,
                                                      int N, int E, int nbuk) {
    __shared__ int cntS[BNODES], A[BNODES], B[BNODES], curS[BNODES], red[256];
    __shared__ float disS[BNODES];
    int t = threadIdx.x;
    int b = blockIdx.x;
    int node0 = b << BSH;
    int nloc = N - node0; if (nloc > BNODES) nloc = BNODES;
    int cntb = cursor[b];
    const unsigned int* ip = inter + (size_t)b * BCAP;

    // inline exclusive bucket base: gB = sum cursor[0..b)
    int partial = 0;
    for (int i = t; i < b; i += 256) partial += cursor[i];
    red[t] = partial;
    __syncthreads();
    for (int off = 128; off > 0; off >>= 1) {
        if (t < off) red[t] += red[t + off];
        __syncthreads();
    }
    int gB = red[0];
    __syncthreads();

    if (t < BNODES) cntS[t] = 0;
    __syncthreads();
    for (int i = t; i < cntb; i += 256)
        atomicAdd(&cntS[ip[i] >> 16], 1);
    __syncthreads();

    int* pa = A; int* pb = B;
    if (t < BNODES) A[t] = cntS[t];
    __syncthreads();
    for (int off = 1; off < BNODES; off <<= 1) {
        if (t < BNODES) pb[t] = pa[t] + (t >= off ? pa[t - off] : 0);
        __syncthreads();
        int* tmp = pa; pa = pb; pb = tmp;
    }
    if (t < BNODES) {
        int excl = pa[t] - cntS[t];
        curS[t] = excl;
        int node = node0 + t;
        if (node < N) {
            rowptr[node] = gB + excl;
            float d = rsqrtf((float)cntS[t] + 1.0f);
            dis[node] = d;
            disS[t] = d;
        }
    }
    if (b == 0 && t == 0) rowptr[N] = E;
    __syncthreads();

    for (int i = t; i < cntb; i += 256) {
        unsigned int w = ip[i];
        int off = atomicAdd(&curS[w >> 16], 1);
        csr16[gB + off] = (unsigned short)(w & 0xffffu);
    }

    for (int i = t; i < nloc * 64; i += 256) {
        int nl = i >> 6, l = i & 63;
        float d = disS[nl];
        float2 v = x2[((size_t)(node0 + nl)) * 64 + l];
        xs[((size_t)(node0 + nl)) * 64 + l] =
            (unsigned int)f2bf(d * v.x) | ((unsigned int)f2bf(d * v.y) << 16);
    }
}

// ---------------- W1 -> fragment-ordered bf16 (+ cursor zeroing) ----------------

__global__ __launch_bounds__(256) void k_w1f_zero(const float* __restrict__ W1,
                                                  unsigned short* __restrict__ W1f,
                                                  int* __restrict__ cursor, int nbuk) {
    int t = blockIdx.x * 256 + threadIdx.x;  // 0..4095
    if (t < nbuk) cursor[t] = 0;
    int lane = t & 63;
    int ks = (t >> 6) & 3;
    int ct = t >> 8;
    int n = ct * 16 + (lane & 15);
    int k0 = ks * 32 + (lane >> 4) * 8;
    unsigned int w[4];
#pragma unroll
    for (int p = 0; p < 4; ++p) {
        unsigned int lo = f2bf(W1[(k0 + 2 * p + 0) * HIDDEN + n]);
        unsigned int hi = f2bf(W1[(k0 + 2 * p + 1) * HIDDEN + n]);
        w[p] = lo | (hi << 16);
    }
    *(uint4*)(W1f + (size_t)t * 8) = make_uint4(w[0], w[1], w[2], w[3]);
}

// ---------------- fused: pull-aggregate (LDS) + MFMA GEMM1 + relu + GEMM2 ----------------
// Block = 4 waves = 32 nodes (2 row-tiles). Gather phase: each wave sums 8 nodes'
// bf16 rows into LDS. Compute phase: each wave owns 4 col-tiles for BOTH row-tiles,
// GEMM2 partials combined across waves via LDS.

__global__ __launch_bounds__(256) void k_fused(const int* __restrict__ rowptr,
                                               const unsigned short* __restrict__ csr16,
                                               const float* __restrict__ dis,
                                               const unsigned int* __restrict__ xs,
                                               const float2* __restrict__ x2,
                                               const unsigned short* __restrict__ W1f,
                                               const float* __restrict__ b1,
                                               const float* __restrict__ W2,
                                               float* __restrict__ Z, int N) {
    __shared__ unsigned int As[MROWS][68];     // bf16x2 rows, stride 68 -> conflict-free
    __shared__ float zred[4][2][16][4];
    int t = threadIdx.x;
    int wave = t >> 6, lane = t & 63;
    int node0 = blockIdx.x * MROWS;

    // ---- gather phase: wave handles nodes node0 + wave*8 .. +7
#pragma unroll
    for (int i = 0; i < 8; ++i) {
        int m = wave * 8 + i;
        int node = node0 + m;
        if (node < N) {
            int beg = rowptr[node];
            int end = rowptr[node + 1];
            float ax = 0.f, ay = 0.f;
            int e = beg;
            for (; e + 7 < end; e += 8) {
                int s0 = csr16[e + 0], s1 = csr16[e + 1], s2 = csr16[e + 2], s3 = csr16[e + 3];
                int s4 = csr16[e + 4], s5 = csr16[e + 5], s6 = csr16[e + 6], s7 = csr16[e + 7];
                unsigned int u0 = xs[(size_t)s0 * 64 + lane];
                unsigned int u1 = xs[(size_t)s1 * 64 + lane];
                unsigned int u2 = xs[(size_t)s2 * 64 + lane];
                unsigned int u3 = xs[(size_t)s3 * 64 + lane];
                unsigned int u4 = xs[(size_t)s4 * 64 + lane];
                unsigned int u5 = xs[(size_t)s5 * 64 + lane];
                unsigned int u6 = xs[(size_t)s6 * 64 + lane];
                unsigned int u7 = xs[(size_t)s7 * 64 + lane];
                ax += bflo(u0) + bflo(u1) + bflo(u2) + bflo(u3) + bflo(u4) + bflo(u5) + bflo(u6) + bflo(u7);
                ay += bfhi(u0) + bfhi(u1) + bfhi(u2) + bfhi(u3) + bfhi(u4) + bfhi(u5) + bfhi(u6) + bfhi(u7);
            }
            for (; e < end; ++e) {
                unsigned int u = xs[(size_t)csr16[e] * 64 + lane];
                ax += bflo(u);
                ay += bfhi(u);
            }
            float dd = dis[node];
            float sd = dd * dd;
            float2 xv = x2[(size_t)node * 64 + lane];
            float ox = dd * ax + sd * xv.x;
            float oy = dd * ay + sd * xv.y;
            As[m][lane] = (unsigned int)f2bf(ox) | ((unsigned int)f2bf(oy) << 16);
        } else {
            As[m][lane] = 0;
        }
    }
    __syncthreads();

    // ---- compute phase
    int q = lane >> 4, c16 = lane & 15;
    short8 a0[4], a1[4];
#pragma unroll
    for (int ks = 0; ks < 4; ++ks) {
        a0[ks] = *(const short8*)&As[c16][ks * 16 + q * 4];
        a1[ks] = *(const short8*)&As[c16 + 16][ks * 16 + q * 4];
    }
    float p0[4][4] = {{0.f}}, p1[4][4] = {{0.f}};
#pragma unroll
    for (int cc = 0; cc < 4; ++cc) {
        int ct = wave * 4 + cc;
        f32x4 c0 = {0.f, 0.f, 0.f, 0.f};
        f32x4 c1 = {0.f, 0.f, 0.f, 0.f};
#pragma unroll
        for (int ks = 0; ks < 4; ++ks) {
            short8 b = *(const short8*)(W1f + ((size_t)((ct * 4 + ks) * 64 + lane)) * 8);
            c0 = __builtin_amdgcn_mfma_f32_16x16x32_bf16(a0[ks], b, c0, 0, 0, 0);
            c1 = __builtin_amdgcn_mfma_f32_16x16x32_bf16(a1[ks], b, c1, 0, 0, 0);
        }
        int n = ct * 16 + c16;
        float bias = b1[n];
        float4 w2v = *(const float4*)(W2 + n * NCLS);
#pragma unroll
        for (int r = 0; r < 4; ++r) {
            float h0 = c0[r] + bias; h0 = h0 > 0.f ? h0 : 0.f;
            float h1 = c1[r] + bias; h1 = h1 > 0.f ? h1 : 0.f;
            p0[r][0] += h0 * w2v.x; p0[r][1] += h0 * w2v.y; p0[r][2] += h0 * w2v.z; p0[r][3] += h0 * w2v.w;
            p1[r][0] += h1 * w2v.x; p1[r][1] += h1 * w2v.y; p1[r][2] += h1 * w2v.z; p1[r][3] += h1 * w2v.w;
        }
    }
#pragma unroll
    for (int m = 1; m < 16; m <<= 1) {
#pragma unroll
        for (int r = 0; r < 4; ++r) {
#pragma unroll
            for (int j = 0; j < 4; ++j) {
                p0[r][j] += __shfl_xor(p0[r][j], m);
                p1[r][j] += __shfl_xor(p1[r][j], m);
            }
        }
    }
    if (c16 == 0) {
#pragma unroll
        for (int r = 0; r < 4; ++r) {
#pragma unroll
            for (int j = 0; j < 4; ++j) {
                zred[wave][0][q * 4 + r][j] = p0[r][j];
                zred[wave][1][q * 4 + r][j] = p1[r][j];
            }
        }
    }
    __syncthreads();
    if (t < 128) {
        int row = t >> 2, j = t & 3;        // row 0..31
        int tile = row >> 4, r16 = row & 15;
        float s = zred[0][tile][r16][j] + zred[1][tile][r16][j] +
                  zred[2][tile][r16][j] + zred[3][tile][r16][j];
        int grow = node0 + row;
        if (grow < N) Z[(size_t)grow * NCLS + j] = s;
    }
}

// ---------------- layer 2: pull-aggregate Z (4 feats) ----------------

__global__ __launch_bounds__(256) void k_pull_z(const int* __restrict__ rowptr,
                                                const unsigned short* __restrict__ csr16,
                                                const float* __restrict__ dis,
                                                const float* __restrict__ Z,
                                                const float* __restrict__ b2,
                                                float* __restrict__ out, int N) {
    int t = blockIdx.x * blockDim.x + threadIdx.x;
    int node = t >> 2;
    int j = t & 3;
    if (node >= N) return;
    int beg = rowptr[node];
    int end = rowptr[node + 1];
    float acc = 0.f;
    for (int e = beg; e < end; ++e) {
        int s = csr16[e];
        acc += dis[s] * Z[(size_t)s * NCLS + j];
    }
    float dd = dis[node];
    out[(size_t)node * NCLS + j] = dd * acc + dd * dd * Z[(size_t)node * NCLS + j] + b2[j];
}

// ---------------- launch ----------------

extern "C" void kernel_launch(void* const* d_in, const int* in_sizes, int n_in,
                              void* d_out, int out_size, void* d_ws, size_t ws_size,
                              hipStream_t stream) {
    const float* x      = (const float*)d_in[0];
    const int*   ei     = (const int*)d_in[1];   // int64 in reference -> int32 in harness
    const float* W1     = (const float*)d_in[2];
    const float* b1     = (const float*)d_in[3];
    const float* W2     = (const float*)d_in[4];
    const float* b2     = (const float*)d_in[5];
    float* out          = (float*)d_out;

    const int N = in_sizes[0] / F_IN;  // 50000
    const int E = in_sizes[1] / 2;     // 800000
    const int* srcIdx = ei;
    const int* dstIdx = ei + E;

    const int nbuk = (N + BNODES - 1) >> BSH;   // 391

    // workspace layout
    unsigned short* xsB  = (unsigned short*)d_ws;        // N*F_IN bf16
    unsigned short* W1f  = xsB + (size_t)N * F_IN;       // 32768 bf16
    float* Z    = (float*)(W1f + 32768);                 // N*NCLS
    float* dis  = Z + (size_t)N * NCLS;                  // N
    int* rowptr = (int*)(dis + N);                       // N+1
    int* cursor = rowptr + N + 1;                        // nbuk
    unsigned short* csr16 = (unsigned short*)(cursor + nbuk);      // E
    unsigned int* inter = (unsigned int*)(csr16 + ((E + 1) & ~1)); // nbuk*BCAP

    k_w1f_zero<<<16, 256, 0, stream>>>(W1, W1f, cursor, nbuk);
    k_bin<<<(E + CHUNK - 1) / CHUNK, 256, 0, stream>>>(srcIdx, dstIdx, cursor, inter, E, nbuk);
    k_bucket_build<<<nbuk, 256, 0, stream>>>(inter, cursor, (const float2*)x,
                                             rowptr, dis, (unsigned int*)xsB, csr16, N, E, nbuk);
    k_fused<<<(N + MROWS - 1) / MROWS, 256, 0, stream>>>(rowptr, csr16, dis,
                                                         (const unsigned int*)xsB, (const float2*)x,
                                                         W1f, b1, W2, Z, N);
    k_pull_z<<<(N * 4 + 255) / 256, 256, 0, stream>>>(rowptr, csr16, dis, Z, b2, out, N);
}